// Round 6
// baseline (426.051 us; speedup 1.0000x reference)
//
#include <hip/hip_runtime.h>
#include <stdint.h>

#define T_TOK 4096
#define DM    512
#define DFF   2048
#define NE    16
#define NSLOT (T_TOK * 2)
#define MAXTILE 80              // max sum ceil(cnt_e/128) = 79

typedef __attribute__((ext_vector_type(8))) short  bf16x8;
typedef __attribute__((ext_vector_type(4))) float  f32x4;
typedef __attribute__((ext_vector_type(8))) unsigned short us8;

static __device__ __forceinline__ unsigned short f2bf(float f) {
    unsigned int u = __float_as_uint(f);
    u += 0x7FFFu + ((u >> 16) & 1u);   // RNE
    return (unsigned short)(u >> 16);
}

static __device__ __forceinline__ void gload_lds16(const void* g, void* l) {
    __builtin_amdgcn_global_load_lds(
        (const __attribute__((address_space(1))) void*)g,
        (__attribute__((address_space(3))) void*)l, 16, 0, 0);
}

// ------- router: fp32 logits, softmax, top-2; also emits x in bf16 -------
__global__ __launch_bounds__(256) void router_kernel(
    const float* __restrict__ x, const float* __restrict__ rw,
    const float* __restrict__ rb, int* __restrict__ tok_e,
    float* __restrict__ tok_g, unsigned short* __restrict__ xb)
{
    __shared__ float rws[NE * DM];
    int tid = threadIdx.x;
    for (int i = 0; i < 8; ++i) {
        int idx = (tid + i * 256) * 4;
        *(f32x4*)&rws[idx] = *(const f32x4*)&rw[idx];
    }
    __syncthreads();

    int wid = tid >> 6, lane = tid & 63;
    int t = blockIdx.x * 4 + wid;

    float xv[8];
    const float* xp = x + (size_t)t * DM + lane * 8;
    *(f32x4*)&xv[0] = *(const f32x4*)xp;
    *(f32x4*)&xv[4] = *(const f32x4*)(xp + 4);

    us8 v;
    for (int i = 0; i < 8; ++i) v[i] = f2bf(xv[i]);
    *(us8*)&xb[(size_t)t * DM + lane * 8] = v;

    float acc[NE];
    for (int e = 0; e < NE; ++e) {
        const float* wp = &rws[e * DM + lane * 8];
        float a = 0.f;
        for (int i = 0; i < 8; ++i) a += xv[i] * wp[i];
        acc[e] = a;
    }
    for (int e = 0; e < NE; ++e) {
        float v2 = acc[e];
        for (int off = 32; off > 0; off >>= 1) v2 += __shfl_xor(v2, off);
        acc[e] = v2 + rb[e];
    }
    float m = acc[0];
    for (int e = 1; e < NE; ++e) m = fmaxf(m, acc[e]);
    float p[NE]; float s = 0.f;
    for (int e = 0; e < NE; ++e) { p[e] = expf(acc[e] - m); s += p[e]; }
    float inv = 1.f / s;
    int i0 = 0; float p0 = p[0];
    for (int e = 1; e < NE; ++e) if (p[e] > p0) { p0 = p[e]; i0 = e; }
    int i1 = (i0 == 0) ? 1 : 0; float p1 = p[i1];
    for (int e = 0; e < NE; ++e)
        if (e != i0 && p[e] > p1) { p1 = p[e]; i1 = e; }
    if (lane == 0) {
        tok_e[t * 2]     = i0;  tok_e[t * 2 + 1] = i1;
        tok_g[t * 2]     = p0 * inv;
        tok_g[t * 2 + 1] = p1 * inv;
    }
}

// -------- compaction: per-expert slot lists + 128-row tile prefix --------
// eoff: [0..15] row offset, [16..31] count, [32..47] tile_base, [48] total
__global__ __launch_bounds__(256) void compact_kernel(
    const int* __restrict__ tok_e, const float* __restrict__ tok_g,
    int* __restrict__ slot_token, float* __restrict__ slot_gate,
    int* __restrict__ eoff)
{
    __shared__ int cnt[NE], cur[NE];
    int tid = threadIdx.x;
    if (tid < NE) cnt[tid] = 0;
    __syncthreads();
    for (int t = tid; t < T_TOK; t += 256) {
        atomicAdd(&cnt[tok_e[t * 2]], 1);
        atomicAdd(&cnt[tok_e[t * 2 + 1]], 1);
    }
    __syncthreads();
    if (tid == 0) {
        int r = 0, tb = 0;
        for (int e = 0; e < NE; ++e) {
            eoff[e] = r; cur[e] = r; r += cnt[e];
            eoff[16 + e] = cnt[e];
            eoff[32 + e] = tb; tb += (cnt[e] + 127) >> 7;
        }
        eoff[48] = tb;
    }
    __syncthreads();
    for (int t = tid; t < T_TOK; t += 256) {
        for (int k = 0; k < 2; ++k) {
            int e = tok_e[t * 2 + k];
            int s = atomicAdd(&cur[e], 1);
            slot_token[s] = t;
            slot_gate[s]  = tok_g[t * 2 + k];
        }
    }
}

// ---- GEMM1: h = gelu(x[gather] @ w1^T + b1) ------------------------------
// Pipelined K-loop: B(kt+1) fp32 reg-prefetch + A(kt+1) gload into As dbuf
// issued BEFORE MFMA(kt); cvt+ds_write after barrier. w1 read fp32 directly.
__global__ __launch_bounds__(256) void gemm1_kernel(
    const unsigned short* __restrict__ xb, const float* __restrict__ w1,
    const float* __restrict__ b1, const int* __restrict__ slot_token,
    const int* __restrict__ eoff, unsigned short* __restrict__ h)
{
    __shared__ unsigned short As[2][8192];   // 2 x 16 KB
    __shared__ unsigned short Bs[8192];      // 16 KB
    __shared__ int tokrow[128];
    __shared__ int meta[49];

    int tid = threadIdx.x, wid = tid >> 6, l = tid & 63;
    int c = l & 15, q = l >> 4;
    if (tid < 49) meta[tid] = eoff[tid];
    __syncthreads();

    int ty = blockIdx.y;
    if (ty >= meta[48]) return;
    int e = 0;
    while (e < NE - 1 && meta[32 + e + 1] <= ty) ++e;
    int mt  = ty - meta[32 + e];
    int off = meta[e], cnt = meta[16 + e];
    int nB    = blockIdx.x * 128;
    int slot0 = off + mt * 128;
    int valid = cnt - mt * 128; if (valid > 128) valid = 128;
    int smax  = off + cnt - 1;

    if (tid < 128) {
        int s = slot0 + tid; if (s > smax) s = smax;
        tokrow[tid] = slot_token[s];
    }
    __syncthreads();

    int rowb = tid >> 1, ch32 = tid & 1;
    const float* bsrc = w1 + ((size_t)e * DFF + nB + rowb) * DM + ch32 * 32;
    int wm = (wid & 1) * 64, wn = (wid >> 1) * 64;

    f32x4 acc[16];
    #pragma unroll
    for (int i = 0; i < 16; ++i) acc[i] = (f32x4){0.f, 0.f, 0.f, 0.f};

    // prologue: A(0) gload + B(0) regs -> LDS
    #pragma unroll
    for (int j = 0; j < 4; ++j) {
        int u = (wid * 4 + j) * 64 + l;
        int row = u >> 3, sc = (u & 7) ^ (row & 7);
        gload_lds16(xb + (size_t)tokrow[row] * DM + sc * 8, &As[0][u * 8]);
    }
    f32x4 br[8];
    #pragma unroll
    for (int i = 0; i < 8; ++i) br[i] = *(const f32x4*)(bsrc + i * 4);
    {
        #pragma unroll
        for (int cc = 0; cc < 4; ++cc) {
            us8 v;
            f32x4 a = br[2 * cc], b = br[2 * cc + 1];
            v[0]=f2bf(a.x); v[1]=f2bf(a.y); v[2]=f2bf(a.z); v[3]=f2bf(a.w);
            v[4]=f2bf(b.x); v[5]=f2bf(b.y); v[6]=f2bf(b.z); v[7]=f2bf(b.w);
            *(us8*)&Bs[rowb * 64 + (((ch32 * 4 + cc) ^ (rowb & 7)) * 8)] = v;
        }
    }
    __syncthreads();   // As[0] drained, Bs(0) ready

    for (int kt = 0; kt < 8; ++kt) {
        int cur = kt & 1;
        if (kt < 7) {
            #pragma unroll
            for (int j = 0; j < 4; ++j) {
                int u = (wid * 4 + j) * 64 + l;
                int row = u >> 3, sc = (u & 7) ^ (row & 7);
                gload_lds16(xb + (size_t)tokrow[row] * DM + (kt + 1) * 64 + sc * 8,
                            &As[1 - cur][u * 8]);
            }
            #pragma unroll
            for (int i = 0; i < 8; ++i)
                br[i] = *(const f32x4*)(bsrc + (kt + 1) * 64 + i * 4);
        }
        #pragma unroll
        for (int ks = 0; ks < 2; ++ks) {
            int sw = ((ks * 4 + q) ^ (c & 7)) * 8;
            bf16x8 af[4], bv[4];
            #pragma unroll
            for (int i = 0; i < 4; ++i)
                af[i] = *(bf16x8*)&As[cur][(wm + i * 16 + c) * 64 + sw];
            #pragma unroll
            for (int j = 0; j < 4; ++j)
                bv[j] = *(bf16x8*)&Bs[(wn + j * 16 + c) * 64 + sw];
            #pragma unroll
            for (int i = 0; i < 4; ++i)
                #pragma unroll
                for (int j = 0; j < 4; ++j)
                    acc[i * 4 + j] = __builtin_amdgcn_mfma_f32_16x16x32_bf16(
                        af[i], bv[j], acc[i * 4 + j], 0, 0, 0);
        }
        __syncthreads();   // MFMA(kt) done; A(kt+1) drained
        if (kt < 7) {
            #pragma unroll
            for (int cc = 0; cc < 4; ++cc) {
                us8 v;
                f32x4 a = br[2 * cc], b = br[2 * cc + 1];
                v[0]=f2bf(a.x); v[1]=f2bf(a.y); v[2]=f2bf(a.z); v[3]=f2bf(a.w);
                v[4]=f2bf(b.x); v[5]=f2bf(b.y); v[6]=f2bf(b.z); v[7]=f2bf(b.w);
                *(us8*)&Bs[rowb * 64 + (((ch32 * 4 + cc) ^ (rowb & 7)) * 8)] = v;
            }
        }
        __syncthreads();   // Bs(kt+1) ready
    }

    // epilogue: bias + exact gelu -> bf16, LDS bounce in 2 row-halves
    float bias[4];
    #pragma unroll
    for (int j = 0; j < 4; ++j) bias[j] = b1[e * DFF + nB + wn + j * 16 + c];
    unsigned short* bounce = &As[0][0];        // [64][136] per phase
    for (int ph = 0; ph < 2; ++ph) {
        __syncthreads();
        if ((wid & 1) == ph) {
            #pragma unroll
            for (int i = 0; i < 4; ++i)
                #pragma unroll
                for (int j = 0; j < 4; ++j) {
                    f32x4 a = acc[i * 4 + j];
                    #pragma unroll
                    for (int r = 0; r < 4; ++r) {
                        int rl = i * 16 + q * 4 + r;
                        float z = a[r] + bias[j];
                        float g = 0.5f * z * (1.f + erff(z * 0.70710678118654752f));
                        bounce[rl * 136 + wn + j * 16 + c] = f2bf(g);
                    }
                }
        }
        __syncthreads();
        #pragma unroll
        for (int it = 0; it < 4; ++it) {
            int u2 = it * 256 + tid;
            int row = u2 >> 4, ch = u2 & 15;
            int gr = ph * 64 + row;
            if (gr < valid)
                *(us8*)&h[(size_t)(slot0 + gr) * DFF + nB + ch * 8] =
                    *(us8*)&bounce[row * 136 + ch * 8];
        }
    }
}

// ---- GEMM2: out += gate*(h @ w2^T + b2), pipelined, K-split x2 ----------
__global__ __launch_bounds__(256) void gemm2_kernel(
    const unsigned short* __restrict__ h, const float* __restrict__ w2,
    const float* __restrict__ b2, const int* __restrict__ slot_token,
    const float* __restrict__ slot_gate, const int* __restrict__ eoff,
    float* __restrict__ out)
{
    __shared__ unsigned short As[2][8192];
    __shared__ unsigned short Bs[8192];
    __shared__ int   tokrow[128];
    __shared__ float grow[128];
    __shared__ int   meta[49];

    int tid = threadIdx.x, wid = tid >> 6, l = tid & 63;
    int c = l & 15, q = l >> 4;
    if (tid < 49) meta[tid] = eoff[tid];
    __syncthreads();

    int ty = blockIdx.y;
    if (ty >= meta[48]) return;
    int e = 0;
    while (e < NE - 1 && meta[32 + e + 1] <= ty) ++e;
    int mt  = ty - meta[32 + e];
    int off = meta[e], cnt = meta[16 + e];
    int nB   = (blockIdx.x & 3) * 128;
    int half = blockIdx.x >> 2;
    int k0   = half * (DFF / 2);
    int slot0 = off + mt * 128;
    int valid = cnt - mt * 128; if (valid > 128) valid = 128;
    int smax  = off + cnt - 1;

    if (tid < 128) {
        int s = slot0 + tid; if (s > smax) s = smax;
        tokrow[tid] = slot_token[s];
        grow[tid]   = slot_gate[s];
    }
    __syncthreads();

    int rowb = tid >> 1, ch32 = tid & 1;
    const float* bsrc = w2 + ((size_t)e * DM + nB + rowb) * DFF + k0 + ch32 * 32;
    int wm = (wid & 1) * 64, wn = (wid >> 1) * 64;

    f32x4 acc[16];
    #pragma unroll
    for (int i = 0; i < 16; ++i) acc[i] = (f32x4){0.f, 0.f, 0.f, 0.f};

    // prologue
    #pragma unroll
    for (int j = 0; j < 4; ++j) {
        int u = (wid * 4 + j) * 64 + l;
        int row = u >> 3, sc = (u & 7) ^ (row & 7);
        int s = slot0 + row; if (s > smax) s = smax;
        gload_lds16(h + (size_t)s * DFF + k0 + sc * 8, &As[0][u * 8]);
    }
    f32x4 br[8];
    #pragma unroll
    for (int i = 0; i < 8; ++i) br[i] = *(const f32x4*)(bsrc + i * 4);
    {
        #pragma unroll
        for (int cc = 0; cc < 4; ++cc) {
            us8 v;
            f32x4 a = br[2 * cc], b = br[2 * cc + 1];
            v[0]=f2bf(a.x); v[1]=f2bf(a.y); v[2]=f2bf(a.z); v[3]=f2bf(a.w);
            v[4]=f2bf(b.x); v[5]=f2bf(b.y); v[6]=f2bf(b.z); v[7]=f2bf(b.w);
            *(us8*)&Bs[rowb * 64 + (((ch32 * 4 + cc) ^ (rowb & 7)) * 8)] = v;
        }
    }
    __syncthreads();

    for (int kt = 0; kt < 16; ++kt) {
        int cur = kt & 1;
        if (kt < 15) {
            #pragma unroll
            for (int j = 0; j < 4; ++j) {
                int u = (wid * 4 + j) * 64 + l;
                int row = u >> 3, sc = (u & 7) ^ (row & 7);
                int s = slot0 + row; if (s > smax) s = smax;
                gload_lds16(h + (size_t)s * DFF + k0 + (kt + 1) * 64 + sc * 8,
                            &As[1 - cur][u * 8]);
            }
            #pragma unroll
            for (int i = 0; i < 8; ++i)
                br[i] = *(const f32x4*)(bsrc + (kt + 1) * 64 + i * 4);
        }
        #pragma unroll
        for (int ks = 0; ks < 2; ++ks) {
            int sw = ((ks * 4 + q) ^ (c & 7)) * 8;
            bf16x8 af[4], bv[4];
            #pragma unroll
            for (int i = 0; i < 4; ++i)
                af[i] = *(bf16x8*)&As[cur][(wm + i * 16 + c) * 64 + sw];
            #pragma unroll
            for (int j = 0; j < 4; ++j)
                bv[j] = *(bf16x8*)&Bs[(wn + j * 16 + c) * 64 + sw];
            #pragma unroll
            for (int i = 0; i < 4; ++i)
                #pragma unroll
                for (int j = 0; j < 4; ++j)
                    acc[i * 4 + j] = __builtin_amdgcn_mfma_f32_16x16x32_bf16(
                        af[i], bv[j], acc[i * 4 + j], 0, 0, 0);
        }
        __syncthreads();
        if (kt < 15) {
            #pragma unroll
            for (int cc = 0; cc < 4; ++cc) {
                us8 v;
                f32x4 a = br[2 * cc], b = br[2 * cc + 1];
                v[0]=f2bf(a.x); v[1]=f2bf(a.y); v[2]=f2bf(a.z); v[3]=f2bf(a.w);
                v[4]=f2bf(b.x); v[5]=f2bf(b.y); v[6]=f2bf(b.z); v[7]=f2bf(b.w);
                *(us8*)&Bs[rowb * 64 + (((ch32 * 4 + cc) ^ (rowb & 7)) * 8)] = v;
            }
        }
        __syncthreads();
    }

    #pragma unroll
    for (int i = 0; i < 4; ++i)
        #pragma unroll
        for (int j = 0; j < 4; ++j) {
            int n = nB + wn + j * 16 + c;
            float bias = (half == 0) ? b2[e * DM + n] : 0.f;
            #pragma unroll
            for (int r = 0; r < 4; ++r) {
                int rl = wm + i * 16 + q * 4 + r;
                if (rl < valid) {
                    float y = acc[i * 4 + j][r] + bias;
                    atomicAdd(&out[(size_t)tokrow[rl] * DM + n], grow[rl] * y);
                }
            }
        }
}

extern "C" void kernel_launch(void* const* d_in, const int* in_sizes, int n_in,
                              void* d_out, int out_size, void* d_ws, size_t ws_size,
                              hipStream_t stream) {
    const float* x  = (const float*)d_in[0];
    const float* rw = (const float*)d_in[1];
    const float* rb = (const float*)d_in[2];
    const float* w1 = (const float*)d_in[3];
    const float* b1 = (const float*)d_in[4];
    const float* w2 = (const float*)d_in[5];
    const float* b2 = (const float*)d_in[6];
    float* out = (float*)d_out;

    char* ws = (char*)d_ws;
    size_t o = 0;
    unsigned short* h  = (unsigned short*)(ws + o); o += (size_t)NSLOT * DFF * 2;
    unsigned short* xb = (unsigned short*)(ws + o); o += (size_t)T_TOK * DM * 2;
    int*   tok_e      = (int*)(ws + o);   o += (size_t)NSLOT * 4;
    float* tok_g      = (float*)(ws + o); o += (size_t)NSLOT * 4;
    int*   slot_token = (int*)(ws + o);   o += (size_t)NSLOT * 4;
    float* slot_gate  = (float*)(ws + o); o += (size_t)NSLOT * 4;
    int*   eoff       = (int*)(ws + o);

    hipMemsetAsync(d_out, 0, (size_t)T_TOK * DM * 4, stream);
    router_kernel<<<T_TOK / 4, 256, 0, stream>>>(x, rw, rb, tok_e, tok_g, xb);
    compact_kernel<<<1, 256, 0, stream>>>(tok_e, tok_g, slot_token, slot_gate, eoff);
    gemm1_kernel<<<dim3(DFF / 128, MAXTILE), 256, 0, stream>>>(
        xb, w1, b1, slot_token, eoff, h);
    gemm2_kernel<<<dim3(8, MAXTILE), 256, 0, stream>>>(
        h, w2, b2, slot_token, slot_gate, eoff, out);
}